// Round 15
// baseline (114.871 us; speedup 1.0000x reference)
//
#include <hip/hip_runtime.h>

// Bidirectional NN-MSE via MFMA — R31: DIAGNOSTIC — TRIPLE-pass ref loop on
// the R13 baseline structure (R22's double-pass undershot the 40us fill
// cutoff; nn_part has NEVER shown a counter row). R30 post-mortem: packed-A
// (bytes/2, fixed geometry) REGRESSED +2.2us => L2 BW falsified; VALU-side
// additions cost ~1:1 => wave-serial path tight. Back-solving pass=14.8us
// (35.5k cyc; ~277 cyc/unit SIMD vs ~64 cyc issued work) only fits if
// waves/SIMD ~2 => VGPR_Count > 128 — which would ALSO explain R19's null
// (its +32 pinned queue regs ate its latency gain) and R28's magnitude.
// Every probe so far was confounded by unobserved occupancy. This probe
// forces nn_part_3x (~44-52us) past the fills into top-5 => first direct
// VGPR_Count / OccupancyPercent / VALUBusy / MfmaUtil / FETCH_SIZE.
// min is idempotent => absmax 0.0; plain-C++ loads must re-issue per rep
// (64KB can't stay live); MMB asm volatile => reps can't fold.
// Pre-committed: VGPR>128 -> R32 cuts registers below the cliff (big win
// predicted). VGPR<=128 & VALUBusy>50% -> R32 pipelines min3(t) under
// MFMA(t+1) (kills 56 nop-cyc/unit). Both low -> convoy; stagger waves.
// dur ~96-115 (throwaway); fills unchanged.
//
//   loss = w * mean_n min_j ||p_n - g_j||^2 + (1-w) * mean_m min_i ||g_m - p_i||^2
//
// d^2 = qq - 2 q.r + rr inside mfma_f32_32x32x16_bf16 (K=16), 2-term bf16
// split per operand (exact bf16xbf16 products; absmax 0 R2-R30).

#define NPTS   16384
#define QBLK   256                // 4 waves x 2 tiles x 32 queries (QT=2)
#define QCH    (NPTS / QBLK)      // 64 query chunks
#define SSPLIT 8                  // ref splits
#define RBLK   (NPTS / SSPLIT)    // 2048 refs streamed per block (64 tiles)
#define NB1    (2 * QCH * SSPLIT) // 1024 blocks

typedef __attribute__((ext_vector_type(8)))  __bf16 bf16x8;
typedef __attribute__((ext_vector_type(16))) float  floatx16;

union frag16 { __bf16 v[16]; uint4 q[2]; };

// One thread per (role, point): builds A-form (ref) and B-form (query)
// fragments. A-form pre-swizzled in MFMA wave order: uint4 index
// (p>>5)*64 + half*32 + (p&31) -> each wave tile read is one contiguous,
// perfectly-coalesced 1 KB global_load_dwordx4 burst.
__global__ __launch_bounds__(256) void prep_kernel(
    const float* __restrict__ pred, const float* __restrict__ gt,
    uint4* __restrict__ aform, uint4* __restrict__ bform,
    float* __restrict__ out)
{
    const int i = blockIdx.x * 256 + threadIdx.x;   // 0 .. 2*NPTS-1
    if (i == 0) out[0] = 0.0f;
    const int role = (i < NPTS) ? 0 : 1;            // 0=pred, 1=gt
    const int p = i - role * NPTS;
    const float* __restrict__ src = role ? gt : pred;

    const float x = src[p * 3 + 0], y = src[p * 3 + 1], z = src[p * 3 + 2];
    const float nn = x * x + y * y + z * z;
    const __bf16 xh = (__bf16)x, yh = (__bf16)y, zh = (__bf16)z;
    const __bf16 xl = (__bf16)(x - (float)xh);
    const __bf16 yl = (__bf16)(y - (float)yh);
    const __bf16 zl = (__bf16)(z - (float)zh);
    const __bf16 nh = (__bf16)nn;
    const __bf16 nl = (__bf16)(nn - (float)nh);
    const __bf16 one = (__bf16)1.0f;

    frag16 A;
    A.v[0]  = (__bf16)(-2.0f * (float)xh); A.v[1]  = A.v[0];
    A.v[2]  = (__bf16)(-2.0f * (float)xl); A.v[3]  = A.v[2];
    A.v[4]  = (__bf16)(-2.0f * (float)yh); A.v[5]  = A.v[4];
    A.v[6]  = (__bf16)(-2.0f * (float)yl); A.v[7]  = A.v[6];
    A.v[8]  = (__bf16)(-2.0f * (float)zh); A.v[9]  = A.v[8];
    A.v[10] = (__bf16)(-2.0f * (float)zl); A.v[11] = A.v[10];
    A.v[12] = nh;  A.v[13] = nl;  A.v[14] = one;  A.v[15] = one;

    frag16 B;
    B.v[0] = xh;  B.v[1]  = xl;  B.v[2]  = xh;  B.v[3]  = xl;
    B.v[4] = yh;  B.v[5]  = yl;  B.v[6]  = yh;  B.v[7]  = yl;
    B.v[8] = zh;  B.v[9]  = zl;  B.v[10] = zh;  B.v[11] = zl;
    B.v[12] = one; B.v[13] = one; B.v[14] = nh;  B.v[15] = nl;

    uint4* da = aform + (size_t)role * (NPTS * 2)
              + ((p >> 5) * 64 + (p & 31));
    da[0]  = A.q[0];        // half 0 (k=0..7)  at +0
    da[32] = A.q[1];        // half 1 (k=8..15) at +32
    uint4* db = bform + (size_t)role * (NPTS * 2) + p * 2;
    db[0] = B.q[0];
    db[1] = B.q[1];
}

// R13's proven asm block: 2 MFMA into fixed dest banks + 16 v_min3 into
// "+v"-pinned accumulators.
#define MFMA_MIN_BLOCK(BQ, M)                                               \
    asm volatile(                                                           \
        "v_mfma_f32_32x32x16_bf16 v[32:47], %[A0], %[B], %[Z]\n\t"          \
        "v_mfma_f32_32x32x16_bf16 v[48:63], %[A1], %[B], %[Z]\n\t"          \
        "s_nop 7\n\ts_nop 7\n\ts_nop 7\n\ts_nop 7\n\t"                      \
        "v_min3_f32 %[M0],  %[M0],  v32, v48\n\t"                           \
        "v_min3_f32 %[M1],  %[M1],  v33, v49\n\t"                           \
        "v_min3_f32 %[M2],  %[M2],  v34, v50\n\t"                           \
        "v_min3_f32 %[M3],  %[M3],  v35, v51\n\t"                           \
        "v_min3_f32 %[M4],  %[M4],  v36, v52\n\t"                           \
        "v_min3_f32 %[M5],  %[M5],  v37, v53\n\t"                           \
        "v_min3_f32 %[M6],  %[M6],  v38, v54\n\t"                           \
        "v_min3_f32 %[M7],  %[M7],  v39, v55\n\t"                           \
        "v_min3_f32 %[M8],  %[M8],  v40, v56\n\t"                           \
        "v_min3_f32 %[M9],  %[M9],  v41, v57\n\t"                           \
        "v_min3_f32 %[M10], %[M10], v42, v58\n\t"                           \
        "v_min3_f32 %[M11], %[M11], v43, v59\n\t"                           \
        "v_min3_f32 %[M12], %[M12], v44, v60\n\t"                           \
        "v_min3_f32 %[M13], %[M13], v45, v61\n\t"                           \
        "v_min3_f32 %[M14], %[M14], v46, v62\n\t"                           \
        "v_min3_f32 %[M15], %[M15], v47, v63"                               \
        : [M0] "+v"(M[0]),  [M1] "+v"(M[1]),  [M2] "+v"(M[2]),              \
          [M3] "+v"(M[3]),  [M4] "+v"(M[4]),  [M5] "+v"(M[5]),              \
          [M6] "+v"(M[6]),  [M7] "+v"(M[7]),  [M8] "+v"(M[8]),              \
          [M9] "+v"(M[9]),  [M10] "+v"(M[10]), [M11] "+v"(M[11]),           \
          [M12] "+v"(M[12]), [M13] "+v"(M[13]), [M14] "+v"(M[14]),          \
          [M15] "+v"(M[15])                                                 \
        : [A0] "v"(a0), [A1] "v"(a1), [B] "v"(BQ), [Z] "v"(zero)            \
        : "v32", "v33", "v34", "v35", "v36", "v37", "v38", "v39",           \
          "v40", "v41", "v42", "v43", "v44", "v45", "v46", "v47",           \
          "v48", "v49", "v50", "v51", "v52", "v53", "v54", "v55",           \
          "v56", "v57", "v58", "v59", "v60", "v61", "v62", "v63")

__global__ __launch_bounds__(256) void nn_part_kernel(
    const uint4* __restrict__ aform, const uint4* __restrict__ bform,
    float* __restrict__ partial)
{
    const int bx   = blockIdx.x;           // 0..NB1-1
    const int dir  = bx >> 9;              // 0: Q=pred,R=gt ; 1: Q=gt,R=pred
    const int qc   = (bx & 511) >> 3;      // 0..63
    const int s    = bx & 7;               // 0..7
    const int tid  = threadIdx.x;
    const int lane = tid & 63;
    const int wave = tid >> 6;
    const int lid  = lane & 31;
    const int half = lane >> 5;

    // dir 0: queries=pred(role 0), refs=gt(role 1); dir 1 swapped
    const uint4* __restrict__ Aref = aform + (size_t)(dir ? 0 : 1) * (NPTS * 2);
    const uint4* __restrict__ Bqry = bform + (size_t)(dir ? 1 : 0) * (NPTS * 2);

    // ---- two query B-fragments per wave (prebuilt, 16 B/lane) ----
    const int qbase = qc * QBLK + wave * 64;
    const bf16x8 bq0 = __builtin_bit_cast(bf16x8, Bqry[(qbase + lid) * 2 + half]);
    const bf16x8 bq1 = __builtin_bit_cast(bf16x8, Bqry[(qbase + 32 + lid) * 2 + half]);

    floatx16 zero;
#pragma unroll
    for (int k = 0; k < 16; ++k) zero[k] = 0.0f;

    float ma[16], mb[16];
#pragma unroll
    for (int k = 0; k < 16; ++k) { ma[k] = 3.4e38f; mb[k] = 3.4e38f; }

    // ---- DIAGNOSTIC triple pass: reps 1,2 are L2-warm re-runs ----
    // min idempotent => bit-identical result; nn_part_3x ~44-52us => TOP-5
    // => first direct VGPR/Occupancy/VALUBusy/MfmaUtil/FETCH counters.
    const uint4* gp0 = Aref + (size_t)s * (RBLK * 2) + half * 32 + lid;
    for (int rep = 0; rep < 3; ++rep) {
        const uint4* gp = gp0;
#pragma unroll 2
        for (int t = 0; t < RBLK / 32; t += 2) {
            const bf16x8 a0 = __builtin_bit_cast(bf16x8, gp[t * 64]);
            const bf16x8 a1 = __builtin_bit_cast(bf16x8, gp[t * 64 + 64]);
            MFMA_MIN_BLOCK(bq0, ma);
            MFMA_MIN_BLOCK(bq1, mb);
        }
    }

    // ---- tail: in-lane trees + one shuffle each, plain coalesced store ----
    float* pout = partial + ((size_t)((dir * QCH + qc) * SSPLIT + s)) * QBLK
                + wave * 64;
    {
        float a = fminf(fminf(ma[0], ma[1]), fminf(ma[2], ma[3]));
        float b = fminf(fminf(ma[4], ma[5]), fminf(ma[6], ma[7]));
        float c = fminf(fminf(ma[8], ma[9]), fminf(ma[10], ma[11]));
        float d = fminf(fminf(ma[12], ma[13]), fminf(ma[14], ma[15]));
        float v = fminf(fminf(a, b), fminf(c, d));
        v = fminf(v, __shfl_xor(v, 32));
        if (half == 0) pout[lid] = v;
    }
    {
        float a = fminf(fminf(mb[0], mb[1]), fminf(mb[2], mb[3]));
        float b = fminf(fminf(mb[4], mb[5]), fminf(mb[6], mb[7]));
        float c = fminf(fminf(mb[8], mb[9]), fminf(mb[10], mb[11]));
        float d = fminf(fminf(mb[12], mb[13]), fminf(mb[14], mb[15]));
        float v = fminf(fminf(a, b), fminf(c, d));
        v = fminf(v, __shfl_xor(v, 32));
        if (half == 0) pout[32 + lid] = v;
    }
}

// Combine: min over the SSPLIT ref-splits per query, weighted sum into out.
__global__ __launch_bounds__(256) void nn_combine_kernel(
    const float* __restrict__ partial, const float* __restrict__ weight,
    float* __restrict__ out)
{
    const int b   = blockIdx.x;        // 0..127 : dir = b>>6, qc = b&63
    const int dir = b >> 6;
    const int qc  = b & 63;
    const int t   = threadIdx.x;

    const float* p = partial + ((size_t)((dir * QCH + qc) * SSPLIT)) * QBLK;
    float v = p[t];
#pragma unroll
    for (int s = 1; s < SSPLIT; ++s)
        v = fminf(v, p[s * QBLK + t]);

    for (int off = 32; off; off >>= 1) v += __shfl_down(v, off);
    __shared__ float ws[4];
    if ((t & 63) == 0) ws[t >> 6] = v;
    __syncthreads();
    if (t == 0) {
        const float sum = ws[0] + ws[1] + ws[2] + ws[3];
        const float wgt = weight[0];
        const float scale = (dir ? (1.0f - wgt) : wgt) / (3.0f * (float)NPTS);
        atomicAdd(out, sum * scale);
    }
}

extern "C" void kernel_launch(void* const* d_in, const int* in_sizes, int n_in,
                              void* d_out, int out_size, void* d_ws, size_t ws_size,
                              hipStream_t stream) {
    const float* pred   = (const float*)d_in[0];
    const float* gt     = (const float*)d_in[1];
    const float* weight = (const float*)d_in[2];

    // ws: [partial 512 KB][aform 1 MB][bform 1 MB]
    float* partial = (float*)d_ws;                       // 2*QCH*SSPLIT*QBLK f32
    uint4* aform = (uint4*)((char*)d_ws + (size_t)2 * QCH * SSPLIT * QBLK * 4);
    uint4* bform = aform + (size_t)2 * NPTS * 2;

    prep_kernel<<<2 * NPTS / 256, 256, 0, stream>>>(pred, gt, aform, bform,
                                                    (float*)d_out);
    nn_part_kernel<<<NB1, 256, 0, stream>>>(aform, bform, partial);
    nn_combine_kernel<<<2 * QCH, 256, 0, stream>>>(partial, weight, (float*)d_out);
}

// Round 17
// 80.780 us; speedup vs baseline: 1.4220x; 1.4220x over previous
//
#include <hip/hip_runtime.h>

// Bidirectional NN-MSE via MFMA — R33: identical resubmit of R32 (never ran:
// GPUAcquisitionTimeout; no kernel signal). Pre-flight re-audit: inline-0
// MAI src2 legal; over-issue tail (<=4KB past slice) in-ws; combine kernel
// consistent with SSPLIT=16 partial layout (2MB).
// Depth-2 counted-vmcnt pipeline with the VGPR bill paid by inline-0 MFMA C
// + SSPLIT=16.
// R31 diagnostic (triple-pass, FIRST nn_part counters): pass=16.8us; VGPR=52
// (no cliff), FETCH=4.6MB (L2-resident, HBM 1.2%), conflicts 0, MfmaUtil
// 34.7, VALUBusy 43.8, Occupancy 33%. All traffic/BW theories dead. Per-iter
// wall 1500 cyc vs 770 demand => ~700 cyc exposed L2 wait shared by 4
// convoying waves => latency/occupancy-bound (rocprof.md row 3). R19's null
// RE-EXPLAINED: its +32 pinned regs => ~136 VGPR => 3 waves/SIMD; occupancy
// loss ate the pipeline gain. Fix: (1) MFMA C = inline 0 (frees 16-reg zero
// bank), (2) depth-2 physical queue v64-79 with s_waitcnt vmcnt(2) — never
// 0 — lead ~1 iter (~250 cyc) > L2 latency, (3) SSPLIT 16 => 2048 blocks,
// 8/CU for balance + extra resident block headroom.
// Net VGPR ~96 => 4-5 waves/SIMD preserved. Predict: pass 16.8 -> 9-11us,
// dur 81.2 -> 74-77; absmax 0. If null at preserved occupancy: exposed
// latency cleanly falsified -> restructure MMB (min3(t-1) under MFMA(t)).
//
//   loss = w * mean_n min_j ||p_n - g_j||^2 + (1-w) * mean_m min_i ||g_m - p_i||^2
//
// d^2 = qq - 2 q.r + rr inside mfma_f32_32x32x16_bf16 (K=16), 2-term bf16
// split per operand (exact bf16xbf16 products; absmax 0 R2-R31).

#define NPTS   16384
#define QBLK   256                // 4 waves x 2 tiles x 32 queries (QT=2)
#define QCH    (NPTS / QBLK)      // 64 query chunks
#define SSPLIT 16                 // ref splits (was 8)
#define RBLK   (NPTS / SSPLIT)    // 1024 refs streamed per block (32 tiles)
#define NB1    (2 * QCH * SSPLIT) // 2048 blocks (8/CU)

typedef __attribute__((ext_vector_type(8)))  __bf16 bf16x8;

union frag16 { __bf16 v[16]; uint4 q[2]; };

// One thread per (role, point): builds A-form (ref) and B-form (query)
// fragments. A-form pre-swizzled in MFMA wave order: uint4 index
// (p>>5)*64 + half*32 + (p&31) -> each wave tile read is one contiguous,
// perfectly-coalesced 1 KB global_load_dwordx4 burst.
__global__ __launch_bounds__(256) void prep_kernel(
    const float* __restrict__ pred, const float* __restrict__ gt,
    uint4* __restrict__ aform, uint4* __restrict__ bform,
    float* __restrict__ out)
{
    const int i = blockIdx.x * 256 + threadIdx.x;   // 0 .. 2*NPTS-1
    if (i == 0) out[0] = 0.0f;
    const int role = (i < NPTS) ? 0 : 1;            // 0=pred, 1=gt
    const int p = i - role * NPTS;
    const float* __restrict__ src = role ? gt : pred;

    const float x = src[p * 3 + 0], y = src[p * 3 + 1], z = src[p * 3 + 2];
    const float nn = x * x + y * y + z * z;
    const __bf16 xh = (__bf16)x, yh = (__bf16)y, zh = (__bf16)z;
    const __bf16 xl = (__bf16)(x - (float)xh);
    const __bf16 yl = (__bf16)(y - (float)yh);
    const __bf16 zl = (__bf16)(z - (float)zh);
    const __bf16 nh = (__bf16)nn;
    const __bf16 nl = (__bf16)(nn - (float)nh);
    const __bf16 one = (__bf16)1.0f;

    frag16 A;
    A.v[0]  = (__bf16)(-2.0f * (float)xh); A.v[1]  = A.v[0];
    A.v[2]  = (__bf16)(-2.0f * (float)xl); A.v[3]  = A.v[2];
    A.v[4]  = (__bf16)(-2.0f * (float)yh); A.v[5]  = A.v[4];
    A.v[6]  = (__bf16)(-2.0f * (float)yl); A.v[7]  = A.v[6];
    A.v[8]  = (__bf16)(-2.0f * (float)zh); A.v[9]  = A.v[8];
    A.v[10] = (__bf16)(-2.0f * (float)zl); A.v[11] = A.v[10];
    A.v[12] = nh;  A.v[13] = nl;  A.v[14] = one;  A.v[15] = one;

    frag16 B;
    B.v[0] = xh;  B.v[1]  = xl;  B.v[2]  = xh;  B.v[3]  = xl;
    B.v[4] = yh;  B.v[5]  = yl;  B.v[6]  = yh;  B.v[7]  = yl;
    B.v[8] = zh;  B.v[9]  = zl;  B.v[10] = zh;  B.v[11] = zl;
    B.v[12] = one; B.v[13] = one; B.v[14] = nh;  B.v[15] = nl;

    uint4* da = aform + (size_t)role * (NPTS * 2)
              + ((p >> 5) * 64 + (p & 31));
    da[0]  = A.q[0];        // half 0 (k=0..7)  at +0
    da[32] = A.q[1];        // half 1 (k=8..15) at +32
    uint4* db = bform + (size_t)role * (NPTS * 2) + p * 2;
    db[0] = B.q[0];
    db[1] = B.q[1];
}

// 2 MFMA (C = inline 0 — no zero register bank) into fixed dest banks
// v[32:63] + 16 v_min3 into "+v"-pinned accumulators. A operands are
// PHYSICAL queue registers (string-pasted).
#define MMB(A0S, A1S, BQ, M)                                                \
    asm volatile(                                                           \
        "v_mfma_f32_32x32x16_bf16 v[32:47], " A0S ", %[B], 0\n\t"           \
        "v_mfma_f32_32x32x16_bf16 v[48:63], " A1S ", %[B], 0\n\t"           \
        "s_nop 7\n\ts_nop 7\n\ts_nop 7\n\ts_nop 7\n\t"                      \
        "v_min3_f32 %[M0],  %[M0],  v32, v48\n\t"                           \
        "v_min3_f32 %[M1],  %[M1],  v33, v49\n\t"                           \
        "v_min3_f32 %[M2],  %[M2],  v34, v50\n\t"                           \
        "v_min3_f32 %[M3],  %[M3],  v35, v51\n\t"                           \
        "v_min3_f32 %[M4],  %[M4],  v36, v52\n\t"                           \
        "v_min3_f32 %[M5],  %[M5],  v37, v53\n\t"                           \
        "v_min3_f32 %[M6],  %[M6],  v38, v54\n\t"                           \
        "v_min3_f32 %[M7],  %[M7],  v39, v55\n\t"                           \
        "v_min3_f32 %[M8],  %[M8],  v40, v56\n\t"                           \
        "v_min3_f32 %[M9],  %[M9],  v41, v57\n\t"                           \
        "v_min3_f32 %[M10], %[M10], v42, v58\n\t"                           \
        "v_min3_f32 %[M11], %[M11], v43, v59\n\t"                           \
        "v_min3_f32 %[M12], %[M12], v44, v60\n\t"                           \
        "v_min3_f32 %[M13], %[M13], v45, v61\n\t"                           \
        "v_min3_f32 %[M14], %[M14], v46, v62\n\t"                           \
        "v_min3_f32 %[M15], %[M15], v47, v63"                               \
        : [M0] "+v"(M[0]),  [M1] "+v"(M[1]),  [M2] "+v"(M[2]),              \
          [M3] "+v"(M[3]),  [M4] "+v"(M[4]),  [M5] "+v"(M[5]),              \
          [M6] "+v"(M[6]),  [M7] "+v"(M[7]),  [M8] "+v"(M[8]),              \
          [M9] "+v"(M[9]),  [M10] "+v"(M[10]), [M11] "+v"(M[11]),           \
          [M12] "+v"(M[12]), [M13] "+v"(M[13]), [M14] "+v"(M[14]),          \
          [M15] "+v"(M[15])                                                 \
        : [B] "v"(BQ)                                                       \
        : "v32", "v33", "v34", "v35", "v36", "v37", "v38", "v39",           \
          "v40", "v41", "v42", "v43", "v44", "v45", "v46", "v47",           \
          "v48", "v49", "v50", "v51", "v52", "v53", "v54", "v55",           \
          "v56", "v57", "v58", "v59", "v60", "v61", "v62", "v63")

// Issue one A tile-pair (2x 1KB global_load_dwordx4) into a queue slot and
// advance the byte offset by 2048. Volatile + hard dests: unmovable.
#define ISSUE(D0S, D1S, C0, C1, C2, C3, C4, C5, C6, C7)                     \
    asm volatile(                                                           \
        "global_load_dwordx4 " D0S ", %[off], %[base]\n\t"                  \
        "global_load_dwordx4 " D1S ", %[off], %[base] offset:1024\n\t"      \
        "v_add_u32 %[off], 0x800, %[off]"                                   \
        : [off] "+v"(voff)                                                  \
        : [base] "s"(abase)                                                 \
        : C0, C1, C2, C3, C4, C5, C6, C7, "memory")

#define ISSUE_A ISSUE("v[64:67]", "v[68:71]", "v64","v65","v66","v67","v68","v69","v70","v71")
#define ISSUE_B ISSUE("v[72:75]", "v[76:79]", "v72","v73","v74","v75","v76","v77","v78","v79")

// Counted wait: oldest pair complete, 1 pair (2 loads) stays in flight.
#define WAIT2 asm volatile("s_waitcnt vmcnt(2)" ::: "memory")

__global__ __launch_bounds__(256) void nn_part_kernel(
    const uint4* __restrict__ aform, const uint4* __restrict__ bform,
    float* __restrict__ partial)
{
    const int bx   = blockIdx.x;           // 0..NB1-1
    const int dir  = bx >> 10;             // 0: Q=pred,R=gt ; 1: Q=gt,R=pred
    const int qc   = (bx >> 4) & 63;       // 0..63
    const int s    = bx & 15;              // 0..15
    const int tid  = threadIdx.x;
    const int lane = tid & 63;
    const int wave = tid >> 6;
    const int lid  = lane & 31;
    const int half = lane >> 5;

    // dir 0: queries=pred(role 0), refs=gt(role 1); dir 1 swapped
    const uint4* __restrict__ Aref = aform + (size_t)(dir ? 0 : 1) * (NPTS * 2);
    const uint4* __restrict__ Bqry = bform + (size_t)(dir ? 1 : 0) * (NPTS * 2);

    // ---- two query B-fragments per wave (prebuilt, 16 B/lane) ----
    const int qbase = qc * QBLK + wave * 64;
    const bf16x8 bq0 = __builtin_bit_cast(bf16x8, Bqry[(qbase + lid) * 2 + half]);
    const bf16x8 bq1 = __builtin_bit_cast(bf16x8, Bqry[(qbase + 32 + lid) * 2 + half]);

    float ma[16], mb[16];
#pragma unroll
    for (int k = 0; k < 16; ++k) { ma[k] = 3.4e38f; mb[k] = 3.4e38f; }

    // Retire compiler-tracked bq loads so OUR vmcnt counts are exact.
    asm volatile("s_waitcnt vmcnt(0)" ::: "memory");

    // ---- depth-2 pipelined A-stream: 4 loads in flight, wait vmcnt(2) ----
    const uint4* abase = Aref + (size_t)s * (RBLK * 2);
    unsigned voff = (unsigned)((half * 32 + lid) * 16);   // byte offset
    ISSUE_A; ISSUE_B;                                     // pairs 0,1

    for (int j = 0; j < 8; ++j) {
        WAIT2; MMB("v[64:67]", "v[68:71]", bq0, ma);
               MMB("v[64:67]", "v[68:71]", bq1, mb); ISSUE_A;
        WAIT2; MMB("v[72:75]", "v[76:79]", bq0, ma);
               MMB("v[72:75]", "v[76:79]", bq1, mb); ISSUE_B;
    }
    asm volatile("s_waitcnt vmcnt(0)" ::: "memory");      // retire over-issue

    // ---- tail: in-lane trees + one shuffle each, plain coalesced store ----
    float* pout = partial + ((size_t)((dir * QCH + qc) * SSPLIT + s)) * QBLK
                + wave * 64;
    {
        float a = fminf(fminf(ma[0], ma[1]), fminf(ma[2], ma[3]));
        float b = fminf(fminf(ma[4], ma[5]), fminf(ma[6], ma[7]));
        float c = fminf(fminf(ma[8], ma[9]), fminf(ma[10], ma[11]));
        float d = fminf(fminf(ma[12], ma[13]), fminf(ma[14], ma[15]));
        float v = fminf(fminf(a, b), fminf(c, d));
        v = fminf(v, __shfl_xor(v, 32));
        if (half == 0) pout[lid] = v;
    }
    {
        float a = fminf(fminf(mb[0], mb[1]), fminf(mb[2], mb[3]));
        float b = fminf(fminf(mb[4], mb[5]), fminf(mb[6], mb[7]));
        float c = fminf(fminf(mb[8], mb[9]), fminf(mb[10], mb[11]));
        float d = fminf(fminf(mb[12], mb[13]), fminf(mb[14], mb[15]));
        float v = fminf(fminf(a, b), fminf(c, d));
        v = fminf(v, __shfl_xor(v, 32));
        if (half == 0) pout[32 + lid] = v;
    }
}

// Combine: min over the SSPLIT ref-splits per query, weighted sum into out.
__global__ __launch_bounds__(256) void nn_combine_kernel(
    const float* __restrict__ partial, const float* __restrict__ weight,
    float* __restrict__ out)
{
    const int b   = blockIdx.x;        // 0..127 : dir = b>>6, qc = b&63
    const int dir = b >> 6;
    const int qc  = b & 63;
    const int t   = threadIdx.x;

    const float* p = partial + ((size_t)((dir * QCH + qc) * SSPLIT)) * QBLK;
    float v = p[t];
#pragma unroll
    for (int s = 1; s < SSPLIT; ++s)
        v = fminf(v, p[(size_t)s * QBLK + t]);

    for (int off = 32; off; off >>= 1) v += __shfl_down(v, off);
    __shared__ float ws[4];
    if ((t & 63) == 0) ws[t >> 6] = v;
    __syncthreads();
    if (t == 0) {
        const float sum = ws[0] + ws[1] + ws[2] + ws[3];
        const float wgt = weight[0];
        const float scale = (dir ? (1.0f - wgt) : wgt) / (3.0f * (float)NPTS);
        atomicAdd(out, sum * scale);
    }
}

extern "C" void kernel_launch(void* const* d_in, const int* in_sizes, int n_in,
                              void* d_out, int out_size, void* d_ws, size_t ws_size,
                              hipStream_t stream) {
    const float* pred   = (const float*)d_in[0];
    const float* gt     = (const float*)d_in[1];
    const float* weight = (const float*)d_in[2];

    // ws: [partial 2 MB][aform 1 MB][bform 1 MB]
    float* partial = (float*)d_ws;                       // 2*QCH*SSPLIT*QBLK f32
    uint4* aform = (uint4*)((char*)d_ws + (size_t)2 * QCH * SSPLIT * QBLK * 4);
    uint4* bform = aform + (size_t)2 * NPTS * 2;

    prep_kernel<<<2 * NPTS / 256, 256, 0, stream>>>(pred, gt, aform, bform,
                                                    (float*)d_out);
    nn_part_kernel<<<NB1, 256, 0, stream>>>(aform, bform, partial);
    nn_combine_kernel<<<2 * QCH, 256, 0, stream>>>(partial, weight, (float*)d_out);
}